// Round 1
// baseline (2103.404 us; speedup 1.0000x reference)
//
#include <hip/hip_runtime.h>

#define NQ      256
#define NK      50000
#define DIM     64
#define TOPK    8
#define QPB     4          // queries per block
#define KSLICES 4          // key slices
#define SLICE   (NK / KSLICES)   // 12500
#define THREADS 512

__device__ __forceinline__ bool lex_less(float d0, int i0, float d1, int i1) {
    return (d0 < d1) || (d0 == d1 && i0 < i1);
}

// insert (d,i) into sorted ascending top-8 kept in registers
__device__ __forceinline__ void insert8(float (&bd)[TOPK], int (&bi)[TOPK], float d, int i) {
    if (!lex_less(d, i, bd[TOPK - 1], bi[TOPK - 1])) return;
    #pragma unroll
    for (int j = TOPK - 1; j > 0; --j) {
        if (lex_less(d, i, bd[j - 1], bi[j - 1])) {
            bd[j] = bd[j - 1]; bi[j] = bi[j - 1];
        } else {
            bd[j] = d; bi[j] = i;
            return;
        }
    }
    bd[0] = d; bi[0] = i;
}

// grid: (KSLICES, NQ/QPB); block: THREADS
__global__ __launch_bounds__(THREADS, 2)
void topk_partial(const float* __restrict__ q, const float* __restrict__ k,
                  float* __restrict__ pd, int* __restrict__ pi)
{
    __shared__ float4 qs4[QPB][DIM / 4];          // 1 KB
    __shared__ float  sd[THREADS * TOPK];         // 16 KB
    __shared__ int    si[THREADS * TOPK];         // 16 KB

    const int tid   = threadIdx.x;
    const int slice = blockIdx.x;
    const int qtile = blockIdx.y;
    const int q0    = qtile * QPB;

    if (tid < QPB * DIM) {
        ((float*)qs4)[tid] = q[q0 * DIM + tid];
    }
    __syncthreads();

    // per-query q_sq (uniform, computed redundantly per thread — cheap)
    float qsq[QPB];
    #pragma unroll
    for (int qq = 0; qq < QPB; ++qq) {
        float s = 0.f;
        const float* qr = (const float*)qs4[qq];
        #pragma unroll
        for (int j = 0; j < DIM; ++j) s += qr[j] * qr[j];
        qsq[qq] = s;
    }

    float bd[QPB][TOPK];
    int   bi[QPB][TOPK];
    #pragma unroll
    for (int qq = 0; qq < QPB; ++qq)
        #pragma unroll
        for (int j = 0; j < TOPK; ++j) { bd[qq][j] = INFINITY; bi[qq][j] = 0x7FFFFFFF; }

    const float4* __restrict__ k4 = (const float4*)k;
    const int base = slice * SLICE;
    const int end  = base + SLICE;

    int n = base + tid;
    // ---- 4-key register tiles ----
    for (; n + 3 * THREADS < end; n += 4 * THREADS) {
        float dot[4][QPB];
        float ksq[4];
        #pragma unroll
        for (int t = 0; t < 4; ++t) {
            ksq[t] = 0.f;
            #pragma unroll
            for (int qq = 0; qq < QPB; ++qq) dot[t][qq] = 0.f;
        }
        #pragma unroll
        for (int c = 0; c < DIM / 4; ++c) {
            float4 kv[4];
            #pragma unroll
            for (int t = 0; t < 4; ++t)
                kv[t] = k4[(size_t)(n + t * THREADS) * (DIM / 4) + c];
            float4 qv[QPB];
            #pragma unroll
            for (int qq = 0; qq < QPB; ++qq) qv[qq] = qs4[qq][c];
            #pragma unroll
            for (int t = 0; t < 4; ++t) {
                ksq[t] += kv[t].x * kv[t].x + kv[t].y * kv[t].y
                        + kv[t].z * kv[t].z + kv[t].w * kv[t].w;
                #pragma unroll
                for (int qq = 0; qq < QPB; ++qq) {
                    dot[t][qq] += qv[qq].x * kv[t].x + qv[qq].y * kv[t].y
                                + qv[qq].z * kv[t].z + qv[qq].w * kv[t].w;
                }
            }
        }
        #pragma unroll
        for (int t = 0; t < 4; ++t) {
            #pragma unroll
            for (int qq = 0; qq < QPB; ++qq) {
                float d2 = (qsq[qq] - 2.0f * dot[t][qq]) + ksq[t];
                insert8(bd[qq], bi[qq], d2, n + t * THREADS);
            }
        }
    }
    // ---- tail (single key) ----
    for (; n < end; n += THREADS) {
        float dot[QPB];
        float ksq = 0.f;
        #pragma unroll
        for (int qq = 0; qq < QPB; ++qq) dot[qq] = 0.f;
        #pragma unroll
        for (int c = 0; c < DIM / 4; ++c) {
            float4 kv = k4[(size_t)n * (DIM / 4) + c];
            ksq += kv.x * kv.x + kv.y * kv.y + kv.z * kv.z + kv.w * kv.w;
            #pragma unroll
            for (int qq = 0; qq < QPB; ++qq) {
                float4 qv = qs4[qq][c];
                dot[qq] += qv.x * kv.x + qv.y * kv.y + qv.z * kv.z + qv.w * kv.w;
            }
        }
        #pragma unroll
        for (int qq = 0; qq < QPB; ++qq) {
            float d2 = (qsq[qq] - 2.0f * dot[qq]) + ksq;
            insert8(bd[qq], bi[qq], d2, n);
        }
    }

    // ---- per-query LDS merge tree: 512 sorted 8-lists -> 1 ----
    for (int qq = 0; qq < QPB; ++qq) {
        __syncthreads();   // protect LDS reuse across qq iterations
        #pragma unroll
        for (int j = 0; j < TOPK; ++j) {
            sd[tid * TOPK + j] = bd[qq][j];
            si[tid * TOPK + j] = bi[qq][j];
        }
        __syncthreads();
        for (int s = THREADS / 2; s >= 1; s >>= 1) {
            if (tid < s) {
                float ad[TOPK], cd[TOPK], rd[TOPK];
                int   ai[TOPK], ci[TOPK], ri[TOPK];
                #pragma unroll
                for (int j = 0; j < TOPK; ++j) {
                    ad[j] = sd[tid * TOPK + j];       ai[j] = si[tid * TOPK + j];
                    cd[j] = sd[(tid + s) * TOPK + j]; ci[j] = si[(tid + s) * TOPK + j];
                }
                int a = 0, b = 0;
                #pragma unroll
                for (int j = 0; j < TOPK; ++j) {
                    bool takeA = lex_less(ad[a], ai[a], cd[b], ci[b]);
                    rd[j] = takeA ? ad[a] : cd[b];
                    ri[j] = takeA ? ai[a] : ci[b];
                    if (takeA) ++a; else ++b;
                }
                #pragma unroll
                for (int j = 0; j < TOPK; ++j) {
                    sd[tid * TOPK + j] = rd[j];
                    si[tid * TOPK + j] = ri[j];
                }
            }
            __syncthreads();
        }
        if (tid < TOPK) {
            int qglob = q0 + qq;
            pd[(qglob * KSLICES + slice) * TOPK + tid] = sd[tid];
            pi[(qglob * KSLICES + slice) * TOPK + tid] = si[tid];
        }
    }
}

// 4-way merge of slice partials -> final indices. 1 block x NQ threads.
__global__ void topk_merge(const float* __restrict__ pd, const int* __restrict__ pi,
                           int* __restrict__ fi)
{
    int qi = threadIdx.x;
    if (qi >= NQ) return;
    int ptr[KSLICES];
    #pragma unroll
    for (int s = 0; s < KSLICES; ++s) ptr[s] = 0;
    for (int j = 0; j < TOPK; ++j) {
        float best = INFINITY; int besti = 0x7FFFFFFF; int bs = 0;
        #pragma unroll
        for (int s = 0; s < KSLICES; ++s) {
            if (ptr[s] < TOPK) {
                float d = pd[(qi * KSLICES + s) * TOPK + ptr[s]];
                int   i = pi[(qi * KSLICES + s) * TOPK + ptr[s]];
                if (lex_less(d, i, best, besti)) { best = d; besti = i; bs = s; }
            }
        }
        fi[qi * TOPK + j] = besti;
        ptr[bs]++;
    }
}

// grid (NQ, TOPK); copy obs[idx] (3072 floats) -> out[(j*NQ+q)*3072]
__global__ __launch_bounds__(256)
void gather_obs(const int* __restrict__ fi, const float* __restrict__ obs,
                float* __restrict__ out)
{
    const int qi = blockIdx.x;
    const int j  = blockIdx.y;
    const int idx = fi[qi * TOPK + j];
    const float4* __restrict__ src = (const float4*)(obs + (size_t)idx * 3072);
    float4* __restrict__ dst = (float4*)(out + ((size_t)j * NQ + qi) * 3072);
    for (int t = threadIdx.x; t < 768; t += 256) dst[t] = src[t];
}

extern "C" void kernel_launch(void* const* d_in, const int* in_sizes, int n_in,
                              void* d_out, int out_size, void* d_ws, size_t ws_size,
                              hipStream_t stream) {
    (void)in_sizes; (void)n_in; (void)out_size; (void)ws_size;
    const float* q   = (const float*)d_in[0];
    const float* k   = (const float*)d_in[1];
    const float* obs = (const float*)d_in[2];
    float* out = (float*)d_out;

    // workspace layout: pd (32 KB) | pi (32 KB) | fi (8 KB)
    float* pd = (float*)d_ws;
    int*   pi = (int*)((char*)d_ws + (size_t)NQ * KSLICES * TOPK * sizeof(float));
    int*   fi = (int*)((char*)d_ws + 2u * NQ * KSLICES * TOPK * sizeof(float));

    topk_partial<<<dim3(KSLICES, NQ / QPB), THREADS, 0, stream>>>(q, k, pd, pi);
    topk_merge<<<1, NQ, 0, stream>>>(pd, pi, fi);
    gather_obs<<<dim3(NQ, TOPK), 256, 0, stream>>>(fi, obs, out);
}